// Round 17
// baseline (885.643 us; speedup 1.0000x reference)
//
#include <hip/hip_runtime.h>
#include <hip/hip_bf16.h>
#include <math.h>

using bf = __hip_bfloat16;
typedef unsigned short u16;
typedef __attribute__((ext_vector_type(8))) unsigned short us8;
typedef __attribute__((ext_vector_type(8))) __bf16 bf16x8;
typedef __attribute__((ext_vector_type(4))) float f32x4;

static constexpr int kC    = 384;
static constexpr int kHid  = 1536;
static constexpr int kHeads= 12;
static constexpr int kN    = 49;
static constexpr float kScale = 0.17677669529663687f;  // 32^-0.5
static constexpr int kWinsTot = 2048;
static constexpr int kRowsTot = kWinsTot * kN;          // 100352

__device__ __forceinline__ float b2f(bf v){ return __bfloat162float(v); }
__device__ __forceinline__ bf    f2b(float v){ return __float2bfloat16(v); }
__device__ __forceinline__ float ldf(const float* p){ return *p; }
__device__ __forceinline__ float ldf(const bf* p){ return b2f(*p); }

// gelu tanh-approx, branch-free: v*(1 - 1/(1+exp2(2.88539*y))), y=v*(c0+c1*v^2)
__device__ __forceinline__ float gelu_f(float v){
  float v2 = v*v;
  float y  = v * (0.7978845608f + 0.0356774081f*v2);
  float e  = __builtin_exp2f(y * 2.885390082f);
  float r  = 1.f / (1.f + e);
  return v - v*r;
}

__device__ __forceinline__ void gload16(const void* g, void* l){
  __builtin_amdgcn_global_load_lds(
      (const __attribute__((address_space(1))) void*)g,
      (__attribute__((address_space(3))) void*)l, 16, 0, 0);
}

// ---------------- weight transpose: out[n*K+k] = bf16(in[k*N+n]) ----------
__global__ void tr_k(const float* __restrict__ in, bf* __restrict__ out, int K, int N){
  int i = blockIdx.x*256 + threadIdx.x;
  if (i < K*N){ int k = i / N, n = i - k*N; out[(size_t)n*K + k] = f2b(in[i]); }
}

// ---- LayerNorm. GATHER=1: fused shift + window partition ----
template<int GATHER, typename TIN>
__global__ __launch_bounds__(256) void ln_k(const TIN* __restrict__ x, const float* __restrict__ g,
                                            const float* __restrict__ be, bf* __restrict__ out,
                                            int winbase){
  int wv = threadIdx.x >> 6, lane = threadIdx.x & 63;
  int lr = blockIdx.x*4 + wv;
  const TIN* src;
  if constexpr (GATHER){
    int win = lr / kN, n = lr - win*kN;
    int gw = winbase + win;
    int b = gw >> 6, rem = gw & 63, wh = rem >> 3, ww = rem & 7;
    int ih = n / 7, iw = n - ih*7;
    int h0 = (wh*7 + ih + 3) % 56;
    int w0 = (ww*7 + iw + 3) % 56;
    src = x + ((size_t)b*3136 + h0*56 + w0) * kC;
  } else {
    src = x + (size_t)lr * kC;
  }
  float vals[6]; float s = 0.f, sq = 0.f;
  #pragma unroll
  for (int j = 0; j < 6; ++j){ float f = ldf(src + j*64 + lane); vals[j] = f; s += f; sq += f*f; }
  #pragma unroll
  for (int o = 32; o > 0; o >>= 1){ s += __shfl_down(s, o); sq += __shfl_down(sq, o); }
  s = __shfl(s, 0); sq = __shfl(sq, 0);
  float mean = s * (1.f/384.f);
  float var  = sq * (1.f/384.f) - mean*mean;
  float rstd = rsqrtf(var + 1e-5f);
  bf* dst = out + (size_t)lr * kC;
  #pragma unroll
  for (int j = 0; j < 6; ++j){
    int c = j*64 + lane;
    dst[c] = f2b((vals[j]-mean)*rstd*g[c] + be[c]);
  }
}

// ---- 2-deep pipelined 128x128 bf16 MFMA GEMM, BK=32, counted vmcnt ----
// Vectorized epilogue via per-wave LDS transpose [16][68] f32 (wave-private,
// no barriers needed: in-wave LDS ordering via compiler lgkmcnt).
template<int EPI, int ALT = 0>
__global__ __launch_bounds__(256, 4) void gemm_k(const bf* __restrict__ A, const bf* __restrict__ Wt,
                                                 const float* __restrict__ bias, int K, int nbn,
                                                 bf* o0, bf* o1, bf* o2,
                                                 float* fo, const void* res, int aux){
  __shared__ char smem[32768];
  u16 (*sA)[4096] = (u16(*)[4096])smem;
  u16 (*sB)[4096] = (u16(*)[4096])(smem + 16384);
  int nwg = gridDim.x, id = blockIdx.x;
  int q = nwg >> 3, r = nwg & 7, xcd = id & 7, off = id >> 3;
  int swz = (xcd < r ? xcd*(q+1) : r*(q+1) + (xcd-r)*q) + off;
  int bm = (swz / nbn) << 7, bn = (swz % nbn) << 7;

  int t = threadIdx.x, lane = t & 63, wv = t >> 6;
  int scol = ((lane & 3) ^ ((lane >> 3) & 3)) * 8;
  const u16* Ag = (const u16*)A  + (size_t)(bm + wv*32 + (lane >> 2))*K + scol;
  const u16* Bg = (const u16*)Wt + (size_t)(bn + wv*32 + (lane >> 2))*K + scol;
  size_t rstep = (size_t)16 * K;
  int l0 = wv*32*32;

  int wr = wv >> 1, wc = wv & 1, lr = lane & 15, lk = lane >> 4;
  int runit = lk ^ ((lr >> 1) & 3);
  int ro = (wr*64 + lr)*32 + runit*8;
  int co = (wc*64 + lr)*32 + runit*8;
  f32x4 acc[4][4];
  #pragma unroll
  for (int i = 0; i < 4; ++i)
    #pragma unroll
    for (int j = 0; j < 4; ++j) acc[i][j] = (f32x4){0.f,0.f,0.f,0.f};

  int nst = K >> 5;                       // 12 or 48 (even)
  #define STG(tt, b) { \
    const u16* ag_ = Ag + (size_t)(tt)*32; const u16* bg_ = Bg + (size_t)(tt)*32; \
    gload16(ag_,         &sA[b][l0]);       gload16(ag_ + rstep, &sA[b][l0 + 512]); \
    gload16(bg_,         &sB[b][l0]);       gload16(bg_ + rstep, &sB[b][l0 + 512]); }
  #define STEP(b, tt) { \
    if ((tt) + 1 < nst) STG((tt) + 1, b ^ 1); \
    if ((tt) + 1 < nst) { asm volatile("s_waitcnt vmcnt(4)" ::: "memory"); } \
    else                { asm volatile("s_waitcnt vmcnt(0)" ::: "memory"); } \
    __builtin_amdgcn_s_barrier(); \
    bf16x8 af[4], bfr[4]; \
    _Pragma("unroll") \
    for (int mi = 0; mi < 4; ++mi) af[mi]  = __builtin_bit_cast(bf16x8, *(const us8*)&sA[b][ro + mi*512]); \
    _Pragma("unroll") \
    for (int ni = 0; ni < 4; ++ni) bfr[ni] = __builtin_bit_cast(bf16x8, *(const us8*)&sB[b][co + ni*512]); \
    __builtin_amdgcn_s_setprio(1); \
    _Pragma("unroll") \
    for (int mi = 0; mi < 4; ++mi) \
      _Pragma("unroll") \
      for (int ni = 0; ni < 4; ++ni) \
        acc[mi][ni] = __builtin_amdgcn_mfma_f32_16x16x32_bf16(af[mi], bfr[ni], acc[mi][ni], 0, 0, 0); \
    __builtin_amdgcn_s_setprio(0); \
    asm volatile("s_waitcnt lgkmcnt(0)" ::: "memory"); \
    __builtin_amdgcn_s_barrier(); }

  STG(0, 0);
  for (int tt = 0; tt < nst; tt += 2){
    STEP(0, tt);
    STEP(1, tt + 1);
  }
  #undef STEP
  #undef STG
  // last STEP's trailing barrier guarantees all waves' ds_reads of sA/sB done.

  // ------------- vectorized epilogue via per-wave LDS transpose -------------
  float* tl = (float*)smem + wv*1088;      // [16][68] f32 per wave (private)
  float bs[4];
  #pragma unroll
  for (int ni = 0; ni < 4; ++ni) bs[ni] = bias[bn + wc*64 + ni*16 + lr];
  int rrow = lane >> 2, cb = (lane & 3) * 16;
  int colg = bn + wc*64 + cb;              // 16 consecutive cols
  #pragma unroll
  for (int mi = 0; mi < 4; ++mi){
    #pragma unroll
    for (int ni = 0; ni < 4; ++ni)
      #pragma unroll
      for (int r2 = 0; r2 < 4; ++r2)
        tl[(lk*4 + r2)*68 + ni*16 + lr] = acc[mi][ni][r2] + bs[ni];
    float vals[16];
    #pragma unroll
    for (int j = 0; j < 16; ++j) vals[j] = tl[rrow*68 + cb + j];
    int row = bm + wr*64 + mi*16 + rrow;
    if constexpr (EPI == 0){
      int which = colg / kC; int cc = colg - which*kC; int hd = cc >> 5, d0 = cc & 31;
      int win = row / kN, n = row - win*kN;
      size_t po = (size_t)(win*kHeads + hd)*2048 + n*32 + d0;
      float sc = which == 0 ? kScale : 1.f;
      bf* dst = which == 0 ? o0 : (which == 1 ? o1 : o2);
      us8 p0, p1;
      #pragma unroll
      for (int j = 0; j < 8; ++j){
        p0[j] = __builtin_bit_cast(u16, f2b(vals[j]   * sc));
        p1[j] = __builtin_bit_cast(u16, f2b(vals[j+8] * sc));
      }
      *(us8*)((u16*)dst + po)     = p0;
      *(us8*)((u16*)dst + po + 8) = p1;
    } else if constexpr (EPI == 1){
      int win = row / kN, n = row - win*kN;
      int gw = aux + win;
      int b = gw >> 6, rem = gw & 63, wh = rem >> 3, ww = rem & 7;
      int ih = n / 7, iw = n - ih*7;
      int h0 = (wh*7 + ih + 3) % 56;
      int w0 = (ww*7 + iw + 3) % 56;
      size_t base = ((size_t)b*3136 + h0*56 + w0)*kC + colg;
      const float* xr = (const float*)res;
      #pragma unroll
      for (int q4 = 0; q4 < 4; ++q4){
        f32x4 rv = *(const f32x4*)(xr + base + q4*4);
        #pragma unroll
        for (int j = 0; j < 4; ++j) vals[q4*4 + j] += rv[j];
      }
      if constexpr (ALT){
        us8 p0, p1;
        #pragma unroll
        for (int j = 0; j < 8; ++j){
          p0[j] = __builtin_bit_cast(u16, f2b(vals[j]));
          p1[j] = __builtin_bit_cast(u16, f2b(vals[j+8]));
        }
        *(us8*)((u16*)o0 + base)     = p0;
        *(us8*)((u16*)o0 + base + 8) = p1;
      } else {
        #pragma unroll
        for (int q4 = 0; q4 < 4; ++q4)
          *(f32x4*)(fo + base + q4*4) = (f32x4){vals[q4*4], vals[q4*4+1], vals[q4*4+2], vals[q4*4+3]};
      }
    } else if constexpr (EPI == 2){
      size_t base = (size_t)row*kHid + colg;
      us8 p0, p1;
      #pragma unroll
      for (int j = 0; j < 16; ++j){
        float v = gelu_f(vals[j]);
        if (j < 8) p0[j] = __builtin_bit_cast(u16, f2b(v));
        else       p1[j-8] = __builtin_bit_cast(u16, f2b(v));
      }
      *(us8*)((u16*)o0 + base)     = p0;
      *(us8*)((u16*)o0 + base + 8) = p1;
    } else {
      size_t base = (size_t)row*kC + colg;
      if constexpr (ALT){
        const u16* xb = (const u16*)res;
        us8 r0 = *(const us8*)(xb + base), r1 = *(const us8*)(xb + base + 8);
        #pragma unroll
        for (int j = 0; j < 8; ++j){
          vals[j]   += b2f(__builtin_bit_cast(bf, (u16)r0[j]));
          vals[j+8] += b2f(__builtin_bit_cast(bf, (u16)r1[j]));
        }
      } else {
        const float* xr = (const float*)res;
        #pragma unroll
        for (int q4 = 0; q4 < 4; ++q4){
          f32x4 rv = *(const f32x4*)(xr + base + q4*4);
          #pragma unroll
          for (int j = 0; j < 4; ++j) vals[q4*4 + j] += rv[j];
        }
      }
      #pragma unroll
      for (int q4 = 0; q4 < 4; ++q4)
        *(f32x4*)(fo + base + q4*4) = (f32x4){vals[q4*4], vals[q4*4+1], vals[q4*4+2], vals[q4*4+3]};
    }
  }
}

// ----------------------- MFMA window attention (v4) -----------------------
__global__ __launch_bounds__(256) void attn_k(const bf* __restrict__ qq, const bf* __restrict__ kk,
                                              const bf* __restrict__ vv, const float* __restrict__ relb,
                                              bf* __restrict__ out){
  __shared__ float rbs[169*kHeads];
  __shared__ u16 plds[4][64*64];
  int t = threadIdx.x, wv = t >> 6, l = t & 63;
  for (int i = t; i < 169*kHeads; i += 256) rbs[i] = relb[i];

  int bid = blockIdx.x*4 + wv, lw = bid / kHeads, h = bid - lw*kHeads;
  const u16* qp = (const u16*)qq + (size_t)bid*2048;
  const u16* kp = (const u16*)kk + (size_t)bid*2048;
  const u16* vp = (const u16*)vv + (size_t)bid*2048;
  int fr = l & 15, fk = l >> 4;

  bf16x8 qf[4], kf[4];
  #pragma unroll
  for (int ti = 0; ti < 4; ++ti){
    qf[ti] = __builtin_bit_cast(bf16x8, *(const us8*)(qp + (ti*16 + fr)*32 + fk*8));
    kf[ti] = __builtin_bit_cast(bf16x8, *(const us8*)(kp + (ti*16 + fr)*32 + fk*8));
  }
  f32x4 s[4][4];
  #pragma unroll
  for (int i = 0; i < 4; ++i)
    #pragma unroll
    for (int j = 0; j < 4; ++j) s[i][j] = (f32x4){0.f,0.f,0.f,0.f};
  #pragma unroll
  for (int ti = 0; ti < 4; ++ti)
    #pragma unroll
    for (int tj = 0; tj < 4; ++tj)
      s[ti][tj] = __builtin_amdgcn_mfma_f32_16x16x32_bf16(qf[ti], kf[tj], s[ti][tj], 0, 0, 0);
  __syncthreads();

  int kh[4], kw[4], cvalid[4];
  #pragma unroll
  for (int tj = 0; tj < 4; ++tj){
    int c = tj*16 + fr;
    kh[tj] = c / 7; kw[tj] = c - kh[tj]*7; cvalid[tj] = c < kN;
  }
  #pragma unroll
  for (int ti = 0; ti < 4; ++ti){
    #pragma unroll
    for (int reg = 0; reg < 4; ++reg){
      int R = ti*16 + fk*4 + reg;
      int Rc = R < kN ? R : kN-1;
      int ih = Rc / 7, iw = Rc - ih*7;
      float v[4];
      #pragma unroll
      for (int tj = 0; tj < 4; ++tj){
        float b = rbs[((ih - kh[tj] + 6)*13 + (iw - kw[tj] + 6))*kHeads + h];
        v[tj] = cvalid[tj] ? s[ti][tj][reg] + b : -1e30f;
      }
      float m = fmaxf(fmaxf(v[0], v[1]), fmaxf(v[2], v[3]));
      #pragma unroll
      for (int msk = 1; msk < 16; msk <<= 1) m = fmaxf(m, __shfl_xor(m, msk));
      float e0 = __expf(v[0]-m), e1 = __expf(v[1]-m), e2 = __expf(v[2]-m), e3 = __expf(v[3]-m);
      float sum = (e0+e1) + (e2+e3);
      #pragma unroll
      for (int msk = 1; msk < 16; msk <<= 1) sum += __shfl_xor(sum, msk);
      float inv = 1.f / sum;
      s[ti][0][reg] = e0*inv; s[ti][1][reg] = e1*inv;
      s[ti][2][reg] = e2*inv; s[ti][3][reg] = e3*inv;
    }
  }
  u16* P = plds[wv];
  #pragma unroll
  for (int ti = 0; ti < 4; ++ti)
    #pragma unroll
    for (int tj = 0; tj < 4; ++tj)
      #pragma unroll
      for (int reg = 0; reg < 4; ++reg){
        int R = ti*16 + fk*4 + reg, c = tj*16 + fr;
        P[R*64 + (((c>>3) ^ (R&7)) << 3) + (c&7)] = __builtin_bit_cast(u16, f2b(s[ti][tj][reg]));
      }
  f32x4 o[4][2];
  #pragma unroll
  for (int i = 0; i < 4; ++i){ o[i][0] = (f32x4){0.f,0.f,0.f,0.f}; o[i][1] = (f32x4){0.f,0.f,0.f,0.f}; }
  #pragma unroll
  for (int ks = 0; ks < 2; ++ks){
    bf16x8 vf[2];
    #pragma unroll
    for (int tdj = 0; tdj < 2; ++tdj){
      us8 tmp;
      #pragma unroll
      for (int j = 0; j < 8; ++j)
        tmp[j] = vp[(ks*32 + fk*8 + j)*32 + tdj*16 + fr];
      vf[tdj] = __builtin_bit_cast(bf16x8, tmp);
    }
    #pragma unroll
    for (int ti = 0; ti < 4; ++ti){
      bf16x8 af = __builtin_bit_cast(bf16x8, *(const us8*)&P[(ti*16 + fr)*64 + (((ks*4 + fk) ^ (fr&7)) << 3)]);
      #pragma unroll
      for (int tdj = 0; tdj < 2; ++tdj)
        o[ti][tdj] = __builtin_amdgcn_mfma_f32_16x16x32_bf16(af, vf[tdj], o[ti][tdj], 0, 0, 0);
    }
  }
  #pragma unroll
  for (int ti = 0; ti < 4; ++ti)
    #pragma unroll
    for (int reg = 0; reg < 4; ++reg){
      int R = ti*16 + fk*4 + reg;
      if (R < kN){
        bf* op = out + ((size_t)lw*kN + R)*kC + h*32;
        #pragma unroll
        for (int tdj = 0; tdj < 2; ++tdj)
          op[tdj*16 + fr] = f2b(o[ti][tdj][reg]);
      }
    }
}

extern "C" void kernel_launch(void* const* d_in, const int* in_sizes, int n_in,
                              void* d_out, int out_size, void* d_ws, size_t ws_size,
                              hipStream_t stream){
  (void)in_sizes; (void)n_in; (void)out_size;
  const float* x     = (const float*)d_in[0];
  const float* n1g   = (const float*)d_in[1];
  const float* n1b   = (const float*)d_in[2];
  const float* qkvw  = (const float*)d_in[3];
  const float* qkvb  = (const float*)d_in[4];
  const float* relb  = (const float*)d_in[5];
  const float* projw = (const float*)d_in[6];
  const float* projb = (const float*)d_in[7];
  const float* n2g   = (const float*)d_in[8];
  const float* n2b   = (const float*)d_in[9];
  const float* fc1w  = (const float*)d_in[10];
  const float* fc1b  = (const float*)d_in[11];
  const float* fc2w  = (const float*)d_in[12];
  const float* fc2b  = (const float*)d_in[13];
  float* out = (float*)d_out;
  char* w = (char*)d_ws;

  const size_t WINB_F = 77070336;    // 100352*384*2 (full-image bf16)
  const size_t BIGB_F = 308281344;   // 100352*1536*2 (hidden full / qkv planes)
  const size_t WTSB   = 3538944;
  const size_t planeF = (size_t)kWinsTot*kHeads*2048;   // 50,331,648 elems
  const size_t NEED_M = WINB_F + BIGB_F + WTSB + WINB_F; // 465,960,960

  if (ws_size >= NEED_M){
    // -------- merged single-pass layout --------
    bf* winbuf = (bf*)w;
    bf* big    = (bf*)(w + WINB_F);
    bf* wts    = (bf*)(w + WINB_F + BIGB_F);
    bf* x1b    = (bf*)(w + WINB_F + BIGB_F + WTSB);
    bf* qkvwt  = wts;
    bf* projwt = qkvwt + 442368;
    bf* fc1wt  = projwt + 147456;
    bf* fc2wt  = fc1wt + 589824;
    bf* qb = big; bf* kb = big + planeF; bf* vb = big + 2*planeF;

    tr_k<<<dim3((442368+255)/256), 256, 0, stream>>>(qkvw,  qkvwt, 384, 1152);
    tr_k<<<dim3((147456+255)/256), 256, 0, stream>>>(projw, projwt, 384, 384);
    tr_k<<<dim3((589824+255)/256), 256, 0, stream>>>(fc1w,  fc1wt, 384, 1536);
    tr_k<<<dim3((589824+255)/256), 256, 0, stream>>>(fc2w,  fc2wt, 1536, 384);
    (void)hipMemsetAsync(vb, 0, planeF*2, stream);   // V pad rows must be 0

    ln_k<1, float><<<kRowsTot/4, 256, 0, stream>>>(x, n1g, n1b, winbuf, 0);
    gemm_k<0><<<784*9, 256, 0, stream>>>(winbuf, qkvwt, qkvb, 384, 9,
                                         qb, kb, vb, nullptr, nullptr, 0);
    attn_k<<<kWinsTot*kHeads/4, 256, 0, stream>>>(qb, kb, vb, relb, winbuf);
    gemm_k<1,1><<<784*3, 256, 0, stream>>>(winbuf, projwt, projb, 384, 3,
                                           x1b, nullptr, nullptr, nullptr, x, 0);
    ln_k<0, bf><<<kRowsTot/4, 256, 0, stream>>>(x1b, n2g, n2b, winbuf, 0);
    gemm_k<2><<<784*12, 256, 0, stream>>>(winbuf, fc1wt, fc1b, 384, 12,
                                          big, nullptr, nullptr, nullptr, nullptr, 0);
    gemm_k<3,1><<<784*3, 256, 0, stream>>>(big, fc2wt, fc2b, 1536, 3,
                                           nullptr, nullptr, nullptr, out, x1b, 0);
  } else {
    // -------- 4-chunk fallback --------
    const int cw = 512, crows = cw*kN;
    const size_t WINB = 19267584, BIGB = 77070336;
    const size_t planeC = (size_t)cw*kHeads*2048;
    bf* winbuf = (bf*)w;
    bf* big    = (bf*)(w + WINB);
    bf* wts    = (bf*)(w + WINB + BIGB);
    bf* qkvwt  = wts;
    bf* projwt = qkvwt + 442368;
    bf* fc1wt  = projwt + 147456;
    bf* fc2wt  = fc1wt + 589824;
    bf* qb = big; bf* kb = big + planeC; bf* vb = big + 2*planeC;

    tr_k<<<dim3((442368+255)/256), 256, 0, stream>>>(qkvw,  qkvwt, 384, 1152);
    tr_k<<<dim3((147456+255)/256), 256, 0, stream>>>(projw, projwt, 384, 384);
    tr_k<<<dim3((589824+255)/256), 256, 0, stream>>>(fc1w,  fc1wt, 384, 1536);
    tr_k<<<dim3((589824+255)/256), 256, 0, stream>>>(fc2w,  fc2wt, 1536, 384);
    (void)hipMemsetAsync(vb, 0, planeC*2, stream);

    for (int c = 0; c < 4; ++c){
      int winbase = c * cw;
      ln_k<1, float><<<crows/4, 256, 0, stream>>>(x, n1g, n1b, winbuf, winbase);
      gemm_k<0><<<196*9, 256, 0, stream>>>(winbuf, qkvwt, qkvb, 384, 9,
                                           qb, kb, vb, nullptr, nullptr, 0);
      attn_k<<<cw*kHeads/4, 256, 0, stream>>>(qb, kb, vb, relb, winbuf);
      gemm_k<1,0><<<196*3, 256, 0, stream>>>(winbuf, projwt, projb, 384, 3,
                                             nullptr, nullptr, nullptr, out, x, winbase);
    }
    for (int c = 0; c < 4; ++c){
      float* xr = out + (size_t)c * crows * kC;
      ln_k<0, float><<<crows/4, 256, 0, stream>>>(xr, n2g, n2b, winbuf, 0);
      gemm_k<2><<<196*12, 256, 0, stream>>>(winbuf, fc1wt, fc1b, 384, 12,
                                            big, nullptr, nullptr, nullptr, nullptr, 0);
      gemm_k<3,0><<<196*3, 256, 0, stream>>>(big, fc2wt, fc2b, 1536, 3,
                                             nullptr, nullptr, nullptr, xr, xr, 0);
    }
  }
}

// Round 18
// 867.887 us; speedup vs baseline: 1.0205x; 1.0205x over previous
//
#include <hip/hip_runtime.h>
#include <hip/hip_bf16.h>
#include <math.h>

using bf = __hip_bfloat16;
typedef unsigned short u16;
typedef __attribute__((ext_vector_type(8))) unsigned short us8;
typedef __attribute__((ext_vector_type(8))) __bf16 bf16x8;
typedef __attribute__((ext_vector_type(4))) float f32x4;

static constexpr int kC    = 384;
static constexpr int kHid  = 1536;
static constexpr int kHeads= 12;
static constexpr int kN    = 49;
static constexpr float kScale = 0.17677669529663687f;  // 32^-0.5
static constexpr int kWinsTot = 2048;
static constexpr int kRowsTot = kWinsTot * kN;          // 100352

__device__ __forceinline__ float b2f(bf v){ return __bfloat162float(v); }
__device__ __forceinline__ bf    f2b(float v){ return __float2bfloat16(v); }
__device__ __forceinline__ float ldf(const float* p){ return *p; }
__device__ __forceinline__ float ldf(const bf* p){ return b2f(*p); }

// gelu tanh-approx, branch-free
__device__ __forceinline__ float gelu_f(float v){
  float v2 = v*v;
  float y  = v * (0.7978845608f + 0.0356774081f*v2);
  float e  = __builtin_exp2f(y * 2.885390082f);
  float r  = 1.f / (1.f + e);
  return v - v*r;
}

__device__ __forceinline__ void gload16(const void* g, void* l){
  __builtin_amdgcn_global_load_lds(
      (const __attribute__((address_space(1))) void*)g,
      (__attribute__((address_space(3))) void*)l, 16, 0, 0);
}

// ---------------- weight transpose: out[n*K+k] = bf16(in[k*N+n]) ----------
__global__ void tr_k(const float* __restrict__ in, bf* __restrict__ out, int K, int N){
  int i = blockIdx.x*256 + threadIdx.x;
  if (i < K*N){ int k = i / N, n = i - k*N; out[(size_t)n*K + k] = f2b(in[i]); }
}

// ---- LayerNorm. GATHER=1: fused shift + window partition ----
template<int GATHER, typename TIN>
__global__ __launch_bounds__(256) void ln_k(const TIN* __restrict__ x, const float* __restrict__ g,
                                            const float* __restrict__ be, bf* __restrict__ out,
                                            int winbase){
  int wv = threadIdx.x >> 6, lane = threadIdx.x & 63;
  int lr = blockIdx.x*4 + wv;
  const TIN* src;
  if constexpr (GATHER){
    int win = lr / kN, n = lr - win*kN;
    int gw = winbase + win;
    int b = gw >> 6, rem = gw & 63, wh = rem >> 3, ww = rem & 7;
    int ih = n / 7, iw = n - ih*7;
    int h0 = (wh*7 + ih + 3) % 56;
    int w0 = (ww*7 + iw + 3) % 56;
    src = x + ((size_t)b*3136 + h0*56 + w0) * kC;
  } else {
    src = x + (size_t)lr * kC;
  }
  float vals[6]; float s = 0.f, sq = 0.f;
  #pragma unroll
  for (int j = 0; j < 6; ++j){ float f = ldf(src + j*64 + lane); vals[j] = f; s += f; sq += f*f; }
  #pragma unroll
  for (int o = 32; o > 0; o >>= 1){ s += __shfl_down(s, o); sq += __shfl_down(sq, o); }
  s = __shfl(s, 0); sq = __shfl(sq, 0);
  float mean = s * (1.f/384.f);
  float var  = sq * (1.f/384.f) - mean*mean;
  float rstd = rsqrtf(var + 1e-5f);
  bf* dst = out + (size_t)lr * kC;
  #pragma unroll
  for (int j = 0; j < 6; ++j){
    int c = j*64 + lane;
    dst[c] = f2b((vals[j]-mean)*rstd*g[c] + be[c]);
  }
}

// ---- 3-buffer pipelined 128x128 bf16 MFMA GEMM, BK=32, counted vmcnt ----
// ~2.5-step load lookahead (vmcnt(8) steady state). LDS 48 KB, 3 blocks/CU.
// Vectorized epilogue via per-wave LDS transpose [16][68] f32 (wave-private).
template<int EPI, int ALT = 0>
__global__ __launch_bounds__(256, 3) void gemm_k(const bf* __restrict__ A, const bf* __restrict__ Wt,
                                                 const float* __restrict__ bias, int K, int nbn,
                                                 bf* o0, bf* o1, bf* o2,
                                                 float* fo, const void* res, int aux){
  __shared__ char smem[49152];
  u16 (*sA)[4096] = (u16(*)[4096])smem;            // 3 x 8 KB
  u16 (*sB)[4096] = (u16(*)[4096])(smem + 24576);  // 3 x 8 KB
  int nwg = gridDim.x, id = blockIdx.x;
  int q = nwg >> 3, r = nwg & 7, xcd = id & 7, off = id >> 3;
  int swz = (xcd < r ? xcd*(q+1) : r*(q+1) + (xcd-r)*q) + off;
  int bm = (swz / nbn) << 7, bn = (swz % nbn) << 7;

  int t = threadIdx.x, lane = t & 63, wv = t >> 6;
  int scol = ((lane & 3) ^ ((lane >> 3) & 3)) * 8;
  const u16* Ag = (const u16*)A  + (size_t)(bm + wv*32 + (lane >> 2))*K + scol;
  const u16* Bg = (const u16*)Wt + (size_t)(bn + wv*32 + (lane >> 2))*K + scol;
  size_t rstep = (size_t)16 * K;
  int l0 = wv*32*32;

  int wr = wv >> 1, wc = wv & 1, lr = lane & 15, lk = lane >> 4;
  int runit = lk ^ ((lr >> 1) & 3);
  int ro = (wr*64 + lr)*32 + runit*8;
  int co = (wc*64 + lr)*32 + runit*8;
  f32x4 acc[4][4];
  #pragma unroll
  for (int i = 0; i < 4; ++i)
    #pragma unroll
    for (int j = 0; j < 4; ++j) acc[i][j] = (f32x4){0.f,0.f,0.f,0.f};

  int nst = K >> 5;                       // 12 or 48 (divisible by 3)
  #define STG(tt, b) { \
    const u16* ag_ = Ag + (size_t)(tt)*32; const u16* bg_ = Bg + (size_t)(tt)*32; \
    gload16(ag_,         &sA[b][l0]);       gload16(ag_ + rstep, &sA[b][l0 + 512]); \
    gload16(bg_,         &sB[b][l0]);       gload16(bg_ + rstep, &sB[b][l0 + 512]); }
  #define STEP(b, tt) { \
    if ((tt) + 2 < nst)      { asm volatile("s_waitcnt vmcnt(8)" ::: "memory"); } \
    else if ((tt) + 1 < nst) { asm volatile("s_waitcnt vmcnt(4)" ::: "memory"); } \
    else                     { asm volatile("s_waitcnt vmcnt(0)" ::: "memory"); } \
    __builtin_amdgcn_s_barrier(); \
    bf16x8 af[4], bfr[4]; \
    _Pragma("unroll") \
    for (int mi = 0; mi < 4; ++mi) af[mi]  = __builtin_bit_cast(bf16x8, *(const us8*)&sA[b][ro + mi*512]); \
    _Pragma("unroll") \
    for (int ni = 0; ni < 4; ++ni) bfr[ni] = __builtin_bit_cast(bf16x8, *(const us8*)&sB[b][co + ni*512]); \
    __builtin_amdgcn_s_setprio(1); \
    _Pragma("unroll") \
    for (int mi = 0; mi < 4; ++mi) \
      _Pragma("unroll") \
      for (int ni = 0; ni < 4; ++ni) \
        acc[mi][ni] = __builtin_amdgcn_mfma_f32_16x16x32_bf16(af[mi], bfr[ni], acc[mi][ni], 0, 0, 0); \
    __builtin_amdgcn_s_setprio(0); \
    asm volatile("s_waitcnt lgkmcnt(0)" ::: "memory"); \
    __builtin_amdgcn_s_barrier(); \
    if ((tt) + 3 < nst) STG((tt) + 3, b); }

  STG(0, 0); STG(1, 1); STG(2, 2);
  for (int tt = 0; tt < nst; tt += 3){
    STEP(0, tt); STEP(1, tt + 1); STEP(2, tt + 2);
  }
  #undef STEP
  #undef STG
  // last STEP's trailing barrier: all waves' ds_reads of sA/sB done.

  // ------------- vectorized epilogue via per-wave LDS transpose -------------
  float* tl = (float*)smem + wv*1088;      // [16][68] f32 per wave (private)
  float bs[4];
  #pragma unroll
  for (int ni = 0; ni < 4; ++ni) bs[ni] = bias[bn + wc*64 + ni*16 + lr];
  int rrow = lane >> 2, cb = (lane & 3) * 16;
  int colg = bn + wc*64 + cb;              // 16 consecutive cols
  #pragma unroll
  for (int mi = 0; mi < 4; ++mi){
    #pragma unroll
    for (int ni = 0; ni < 4; ++ni)
      #pragma unroll
      for (int r2 = 0; r2 < 4; ++r2)
        tl[(lk*4 + r2)*68 + ni*16 + lr] = acc[mi][ni][r2] + bs[ni];
    float vals[16];
    #pragma unroll
    for (int j = 0; j < 16; ++j) vals[j] = tl[rrow*68 + cb + j];
    int row = bm + wr*64 + mi*16 + rrow;
    if constexpr (EPI == 0){
      int which = colg / kC; int cc = colg - which*kC; int hd = cc >> 5, d0 = cc & 31;
      int win = row / kN, n = row - win*kN;
      size_t po = (size_t)(win*kHeads + hd)*2048 + n*32 + d0;
      float sc = which == 0 ? kScale : 1.f;
      bf* dst = which == 0 ? o0 : (which == 1 ? o1 : o2);
      us8 p0, p1;
      #pragma unroll
      for (int j = 0; j < 8; ++j){
        p0[j] = __builtin_bit_cast(u16, f2b(vals[j]   * sc));
        p1[j] = __builtin_bit_cast(u16, f2b(vals[j+8] * sc));
      }
      *(us8*)((u16*)dst + po)     = p0;
      *(us8*)((u16*)dst + po + 8) = p1;
    } else if constexpr (EPI == 1){
      int win = row / kN, n = row - win*kN;
      int gw = aux + win;
      int b = gw >> 6, rem = gw & 63, wh = rem >> 3, ww = rem & 7;
      int ih = n / 7, iw = n - ih*7;
      int h0 = (wh*7 + ih + 3) % 56;
      int w0 = (ww*7 + iw + 3) % 56;
      size_t base = ((size_t)b*3136 + h0*56 + w0)*kC + colg;
      const float* xr = (const float*)res;
      #pragma unroll
      for (int q4 = 0; q4 < 4; ++q4){
        f32x4 rv = *(const f32x4*)(xr + base + q4*4);
        #pragma unroll
        for (int j = 0; j < 4; ++j) vals[q4*4 + j] += rv[j];
      }
      if constexpr (ALT){
        us8 p0, p1;
        #pragma unroll
        for (int j = 0; j < 8; ++j){
          p0[j] = __builtin_bit_cast(u16, f2b(vals[j]));
          p1[j] = __builtin_bit_cast(u16, f2b(vals[j+8]));
        }
        *(us8*)((u16*)o0 + base)     = p0;
        *(us8*)((u16*)o0 + base + 8) = p1;
      } else {
        #pragma unroll
        for (int q4 = 0; q4 < 4; ++q4)
          *(f32x4*)(fo + base + q4*4) = (f32x4){vals[q4*4], vals[q4*4+1], vals[q4*4+2], vals[q4*4+3]};
      }
    } else if constexpr (EPI == 2){
      size_t base = (size_t)row*kHid + colg;
      us8 p0, p1;
      #pragma unroll
      for (int j = 0; j < 16; ++j){
        float v = gelu_f(vals[j]);
        if (j < 8) p0[j] = __builtin_bit_cast(u16, f2b(v));
        else       p1[j-8] = __builtin_bit_cast(u16, f2b(v));
      }
      *(us8*)((u16*)o0 + base)     = p0;
      *(us8*)((u16*)o0 + base + 8) = p1;
    } else {
      size_t base = (size_t)row*kC + colg;
      if constexpr (ALT){
        const u16* xb = (const u16*)res;
        us8 r0 = *(const us8*)(xb + base), r1 = *(const us8*)(xb + base + 8);
        #pragma unroll
        for (int j = 0; j < 8; ++j){
          vals[j]   += b2f(__builtin_bit_cast(bf, (u16)r0[j]));
          vals[j+8] += b2f(__builtin_bit_cast(bf, (u16)r1[j]));
        }
      } else {
        const float* xr = (const float*)res;
        #pragma unroll
        for (int q4 = 0; q4 < 4; ++q4){
          f32x4 rv = *(const f32x4*)(xr + base + q4*4);
          #pragma unroll
          for (int j = 0; j < 4; ++j) vals[q4*4 + j] += rv[j];
        }
      }
      #pragma unroll
      for (int q4 = 0; q4 < 4; ++q4)
        *(f32x4*)(fo + base + q4*4) = (f32x4){vals[q4*4], vals[q4*4+1], vals[q4*4+2], vals[q4*4+3]};
    }
  }
}

// ----------------------- MFMA window attention (v4) -----------------------
// V plane ROW-major [64][32]. Pad keys (n>=49) are masked to P=0 exactly, so
// pad V contents only need to be FINITE (0xAA poison bf16 is finite) — no memset.
__global__ __launch_bounds__(256) void attn_k(const bf* __restrict__ qq, const bf* __restrict__ kk,
                                              const bf* __restrict__ vv, const float* __restrict__ relb,
                                              bf* __restrict__ out){
  __shared__ float rbs[169*kHeads];
  __shared__ u16 plds[4][64*64];
  int t = threadIdx.x, wv = t >> 6, l = t & 63;
  for (int i = t; i < 169*kHeads; i += 256) rbs[i] = relb[i];

  int bid = blockIdx.x*4 + wv, lw = bid / kHeads, h = bid - lw*kHeads;
  const u16* qp = (const u16*)qq + (size_t)bid*2048;
  const u16* kp = (const u16*)kk + (size_t)bid*2048;
  const u16* vp = (const u16*)vv + (size_t)bid*2048;
  int fr = l & 15, fk = l >> 4;

  bf16x8 qf[4], kf[4];
  #pragma unroll
  for (int ti = 0; ti < 4; ++ti){
    qf[ti] = __builtin_bit_cast(bf16x8, *(const us8*)(qp + (ti*16 + fr)*32 + fk*8));
    kf[ti] = __builtin_bit_cast(bf16x8, *(const us8*)(kp + (ti*16 + fr)*32 + fk*8));
  }
  f32x4 s[4][4];
  #pragma unroll
  for (int i = 0; i < 4; ++i)
    #pragma unroll
    for (int j = 0; j < 4; ++j) s[i][j] = (f32x4){0.f,0.f,0.f,0.f};
  #pragma unroll
  for (int ti = 0; ti < 4; ++ti)
    #pragma unroll
    for (int tj = 0; tj < 4; ++tj)
      s[ti][tj] = __builtin_amdgcn_mfma_f32_16x16x32_bf16(qf[ti], kf[tj], s[ti][tj], 0, 0, 0);
  __syncthreads();

  int kh[4], kw[4], cvalid[4];
  #pragma unroll
  for (int tj = 0; tj < 4; ++tj){
    int c = tj*16 + fr;
    kh[tj] = c / 7; kw[tj] = c - kh[tj]*7; cvalid[tj] = c < kN;
  }
  #pragma unroll
  for (int ti = 0; ti < 4; ++ti){
    #pragma unroll
    for (int reg = 0; reg < 4; ++reg){
      int R = ti*16 + fk*4 + reg;
      int Rc = R < kN ? R : kN-1;
      int ih = Rc / 7, iw = Rc - ih*7;
      float v[4];
      #pragma unroll
      for (int tj = 0; tj < 4; ++tj){
        float b = rbs[((ih - kh[tj] + 6)*13 + (iw - kw[tj] + 6))*kHeads + h];
        v[tj] = cvalid[tj] ? s[ti][tj][reg] + b : -1e30f;
      }
      float m = fmaxf(fmaxf(v[0], v[1]), fmaxf(v[2], v[3]));
      #pragma unroll
      for (int msk = 1; msk < 16; msk <<= 1) m = fmaxf(m, __shfl_xor(m, msk));
      float e0 = __expf(v[0]-m), e1 = __expf(v[1]-m), e2 = __expf(v[2]-m), e3 = __expf(v[3]-m);
      float sum = (e0+e1) + (e2+e3);
      #pragma unroll
      for (int msk = 1; msk < 16; msk <<= 1) sum += __shfl_xor(sum, msk);
      float inv = 1.f / sum;
      s[ti][0][reg] = e0*inv; s[ti][1][reg] = e1*inv;
      s[ti][2][reg] = e2*inv; s[ti][3][reg] = e3*inv;
    }
  }
  u16* P = plds[wv];
  #pragma unroll
  for (int ti = 0; ti < 4; ++ti)
    #pragma unroll
    for (int tj = 0; tj < 4; ++tj)
      #pragma unroll
      for (int reg = 0; reg < 4; ++reg){
        int R = ti*16 + fk*4 + reg, c = tj*16 + fr;
        P[R*64 + (((c>>3) ^ (R&7)) << 3) + (c&7)] = __builtin_bit_cast(u16, f2b(s[ti][tj][reg]));
      }
  f32x4 o[4][2];
  #pragma unroll
  for (int i = 0; i < 4; ++i){ o[i][0] = (f32x4){0.f,0.f,0.f,0.f}; o[i][1] = (f32x4){0.f,0.f,0.f,0.f}; }
  #pragma unroll
  for (int ks = 0; ks < 2; ++ks){
    bf16x8 vf[2];
    #pragma unroll
    for (int tdj = 0; tdj < 2; ++tdj){
      us8 tmp;
      #pragma unroll
      for (int j = 0; j < 8; ++j)
        tmp[j] = vp[(ks*32 + fk*8 + j)*32 + tdj*16 + fr];
      vf[tdj] = __builtin_bit_cast(bf16x8, tmp);
    }
    #pragma unroll
    for (int ti = 0; ti < 4; ++ti){
      bf16x8 af = __builtin_bit_cast(bf16x8, *(const us8*)&P[(ti*16 + fr)*64 + (((ks*4 + fk) ^ (fr&7)) << 3)]);
      #pragma unroll
      for (int tdj = 0; tdj < 2; ++tdj)
        o[ti][tdj] = __builtin_amdgcn_mfma_f32_16x16x32_bf16(af, vf[tdj], o[ti][tdj], 0, 0, 0);
    }
  }
  #pragma unroll
  for (int ti = 0; ti < 4; ++ti)
    #pragma unroll
    for (int reg = 0; reg < 4; ++reg){
      int R = ti*16 + fk*4 + reg;
      if (R < kN){
        bf* op = out + ((size_t)lw*kN + R)*kC + h*32;
        #pragma unroll
        for (int tdj = 0; tdj < 2; ++tdj)
          op[tdj*16 + fr] = f2b(o[ti][tdj][reg]);
      }
    }
}

extern "C" void kernel_launch(void* const* d_in, const int* in_sizes, int n_in,
                              void* d_out, int out_size, void* d_ws, size_t ws_size,
                              hipStream_t stream){
  (void)in_sizes; (void)n_in; (void)out_size;
  const float* x     = (const float*)d_in[0];
  const float* n1g   = (const float*)d_in[1];
  const float* n1b   = (const float*)d_in[2];
  const float* qkvw  = (const float*)d_in[3];
  const float* qkvb  = (const float*)d_in[4];
  const float* relb  = (const float*)d_in[5];
  const float* projw = (const float*)d_in[6];
  const float* projb = (const float*)d_in[7];
  const float* n2g   = (const float*)d_in[8];
  const float* n2b   = (const float*)d_in[9];
  const float* fc1w  = (const float*)d_in[10];
  const float* fc1b  = (const float*)d_in[11];
  const float* fc2w  = (const float*)d_in[12];
  const float* fc2b  = (const float*)d_in[13];
  float* out = (float*)d_out;
  char* w = (char*)d_ws;

  const size_t WINB_F = 77070336;    // 100352*384*2 (full-image bf16)
  const size_t BIGB_F = 308281344;   // 100352*1536*2 (hidden full / qkv planes)
  const size_t WTSB   = 3538944;
  const size_t planeF = (size_t)kWinsTot*kHeads*2048;   // 50,331,648 elems
  const size_t NEED_M = WINB_F + BIGB_F + WTSB + WINB_F; // 465,960,960

  if (ws_size >= NEED_M){
    // -------- merged single-pass layout --------
    bf* winbuf = (bf*)w;
    bf* big    = (bf*)(w + WINB_F);
    bf* wts    = (bf*)(w + WINB_F + BIGB_F);
    bf* x1b    = (bf*)(w + WINB_F + BIGB_F + WTSB);
    bf* qkvwt  = wts;
    bf* projwt = qkvwt + 442368;
    bf* fc1wt  = projwt + 147456;
    bf* fc2wt  = fc1wt + 589824;
    bf* qb = big; bf* kb = big + planeF; bf* vb = big + 2*planeF;

    tr_k<<<dim3((442368+255)/256), 256, 0, stream>>>(qkvw,  qkvwt, 384, 1152);
    tr_k<<<dim3((147456+255)/256), 256, 0, stream>>>(projw, projwt, 384, 384);
    tr_k<<<dim3((589824+255)/256), 256, 0, stream>>>(fc1w,  fc1wt, 384, 1536);
    tr_k<<<dim3((589824+255)/256), 256, 0, stream>>>(fc2w,  fc2wt, 1536, 384);

    ln_k<1, float><<<kRowsTot/4, 256, 0, stream>>>(x, n1g, n1b, winbuf, 0);
    gemm_k<0><<<784*9, 256, 0, stream>>>(winbuf, qkvwt, qkvb, 384, 9,
                                         qb, kb, vb, nullptr, nullptr, 0);
    attn_k<<<kWinsTot*kHeads/4, 256, 0, stream>>>(qb, kb, vb, relb, winbuf);
    gemm_k<1,1><<<784*3, 256, 0, stream>>>(winbuf, projwt, projb, 384, 3,
                                           x1b, nullptr, nullptr, nullptr, x, 0);
    ln_k<0, bf><<<kRowsTot/4, 256, 0, stream>>>(x1b, n2g, n2b, winbuf, 0);
    gemm_k<2><<<784*12, 256, 0, stream>>>(winbuf, fc1wt, fc1b, 384, 12,
                                          big, nullptr, nullptr, nullptr, nullptr, 0);
    gemm_k<3,1><<<784*3, 256, 0, stream>>>(big, fc2wt, fc2b, 1536, 3,
                                           nullptr, nullptr, nullptr, out, x1b, 0);
  } else {
    // -------- 4-chunk fallback --------
    const int cw = 512, crows = cw*kN;
    const size_t WINB = 19267584, BIGB = 77070336;
    const size_t planeC = (size_t)cw*kHeads*2048;
    bf* winbuf = (bf*)w;
    bf* big    = (bf*)(w + WINB);
    bf* wts    = (bf*)(w + WINB + BIGB);
    bf* qkvwt  = wts;
    bf* projwt = qkvwt + 442368;
    bf* fc1wt  = projwt + 147456;
    bf* fc2wt  = fc1wt + 589824;
    bf* qb = big; bf* kb = big + planeC; bf* vb = big + 2*planeC;

    tr_k<<<dim3((442368+255)/256), 256, 0, stream>>>(qkvw,  qkvwt, 384, 1152);
    tr_k<<<dim3((147456+255)/256), 256, 0, stream>>>(projw, projwt, 384, 384);
    tr_k<<<dim3((589824+255)/256), 256, 0, stream>>>(fc1w,  fc1wt, 384, 1536);
    tr_k<<<dim3((589824+255)/256), 256, 0, stream>>>(fc2w,  fc2wt, 1536, 384);

    for (int c = 0; c < 4; ++c){
      int winbase = c * cw;
      ln_k<1, float><<<crows/4, 256, 0, stream>>>(x, n1g, n1b, winbuf, winbase);
      gemm_k<0><<<196*9, 256, 0, stream>>>(winbuf, qkvwt, qkvb, 384, 9,
                                           qb, kb, vb, nullptr, nullptr, 0);
      attn_k<<<cw*kHeads/4, 256, 0, stream>>>(qb, kb, vb, relb, winbuf);
      gemm_k<1,0><<<196*3, 256, 0, stream>>>(winbuf, projwt, projb, 384, 3,
                                             nullptr, nullptr, nullptr, out, x, winbase);
    }
    for (int c = 0; c < 4; ++c){
      float* xr = out + (size_t)c * crows * kC;
      ln_k<0, float><<<crows/4, 256, 0, stream>>>(xr, n2g, n2b, winbuf, 0);
      gemm_k<2><<<196*12, 256, 0, stream>>>(winbuf, fc1wt, fc1b, 384, 12,
                                            big, nullptr, nullptr, nullptr, nullptr, 0);
      gemm_k<3,0><<<196*3, 256, 0, stream>>>(big, fc2wt, fc2b, 1536, 3,
                                             nullptr, nullptr, nullptr, xr, xr, 0);
    }
  }
}

// Round 19
// 838.513 us; speedup vs baseline: 1.0562x; 1.0350x over previous
//
#include <hip/hip_runtime.h>
#include <hip/hip_bf16.h>
#include <math.h>

using bf = __hip_bfloat16;
typedef unsigned short u16;
typedef __attribute__((ext_vector_type(8))) unsigned short us8;
typedef __attribute__((ext_vector_type(8))) __bf16 bf16x8;
typedef __attribute__((ext_vector_type(4))) float f32x4;

static constexpr int kC    = 384;
static constexpr int kHid  = 1536;
static constexpr int kHeads= 12;
static constexpr int kN    = 49;
static constexpr float kScale = 0.17677669529663687f;  // 32^-0.5
static constexpr int kWinsTot = 2048;
static constexpr int kRowsTot = kWinsTot * kN;          // 100352

__device__ __forceinline__ float b2f(bf v){ return __bfloat162float(v); }
__device__ __forceinline__ bf    f2b(float v){ return __float2bfloat16(v); }
__device__ __forceinline__ float ldf(const float* p){ return *p; }
__device__ __forceinline__ float ldf(const bf* p){ return b2f(*p); }

// gelu tanh-approx with raw HW ops: v_exp_f32 + v_rcp_f32 (~9 inst total)
__device__ __forceinline__ float gelu_f(float v){
  float v2 = v*v;
  float y  = v * (0.7978845608f + 0.0356774081f*v2);
  float e  = __builtin_amdgcn_exp2f(y * 2.885390082f);
  float r  = __builtin_amdgcn_rcpf(1.f + e);
  return v - v*r;
}

__device__ __forceinline__ void gload16(const void* g, void* l){
  __builtin_amdgcn_global_load_lds(
      (const __attribute__((address_space(1))) void*)g,
      (__attribute__((address_space(3))) void*)l, 16, 0, 0);
}

// ---------------- weight transpose: out[n*K+k] = bf16(in[k*N+n]) ----------
__global__ void tr_k(const float* __restrict__ in, bf* __restrict__ out, int K, int N){
  int i = blockIdx.x*256 + threadIdx.x;
  if (i < K*N){ int k = i / N, n = i - k*N; out[(size_t)n*K + k] = f2b(in[i]); }
}

// ---- LayerNorm. GATHER=1: fused shift + window partition ----
template<int GATHER, typename TIN>
__global__ __launch_bounds__(256) void ln_k(const TIN* __restrict__ x, const float* __restrict__ g,
                                            const float* __restrict__ be, bf* __restrict__ out,
                                            int winbase){
  int wv = threadIdx.x >> 6, lane = threadIdx.x & 63;
  int lr = blockIdx.x*4 + wv;
  const TIN* src;
  if constexpr (GATHER){
    int win = lr / kN, n = lr - win*kN;
    int gw = winbase + win;
    int b = gw >> 6, rem = gw & 63, wh = rem >> 3, ww = rem & 7;
    int ih = n / 7, iw = n - ih*7;
    int h0 = (wh*7 + ih + 3) % 56;
    int w0 = (ww*7 + iw + 3) % 56;
    src = x + ((size_t)b*3136 + h0*56 + w0) * kC;
  } else {
    src = x + (size_t)lr * kC;
  }
  float vals[6]; float s = 0.f, sq = 0.f;
  #pragma unroll
  for (int j = 0; j < 6; ++j){ float f = ldf(src + j*64 + lane); vals[j] = f; s += f; sq += f*f; }
  #pragma unroll
  for (int o = 32; o > 0; o >>= 1){ s += __shfl_down(s, o); sq += __shfl_down(sq, o); }
  s = __shfl(s, 0); sq = __shfl(sq, 0);
  float mean = s * (1.f/384.f);
  float var  = sq * (1.f/384.f) - mean*mean;
  float rstd = rsqrtf(var + 1e-5f);
  bf* dst = out + (size_t)lr * kC;
  #pragma unroll
  for (int j = 0; j < 6; ++j){
    int c = j*64 + lane;
    dst[c] = f2b((vals[j]-mean)*rstd*g[c] + be[c]);
  }
}

// ---- 3-buffer pipelined 128x128 bf16 MFMA GEMM, BK=32, counted vmcnt ----
template<int EPI, int ALT = 0>
__global__ __launch_bounds__(256, 3) void gemm_k(const bf* __restrict__ A, const bf* __restrict__ Wt,
                                                 const float* __restrict__ bias, int K, int nbn,
                                                 bf* o0, bf* o1, bf* o2,
                                                 float* fo, const void* res, int aux){
  __shared__ char smem[49152];
  u16 (*sA)[4096] = (u16(*)[4096])smem;            // 3 x 8 KB
  u16 (*sB)[4096] = (u16(*)[4096])(smem + 24576);  // 3 x 8 KB
  int nwg = gridDim.x, id = blockIdx.x;
  int q = nwg >> 3, r = nwg & 7, xcd = id & 7, off = id >> 3;
  int swz = (xcd < r ? xcd*(q+1) : r*(q+1) + (xcd-r)*q) + off;
  int bm = (swz / nbn) << 7, bn = (swz % nbn) << 7;

  int t = threadIdx.x, lane = t & 63, wv = t >> 6;
  int scol = ((lane & 3) ^ ((lane >> 3) & 3)) * 8;
  const u16* Ag = (const u16*)A  + (size_t)(bm + wv*32 + (lane >> 2))*K + scol;
  const u16* Bg = (const u16*)Wt + (size_t)(bn + wv*32 + (lane >> 2))*K + scol;
  size_t rstep = (size_t)16 * K;
  int l0 = wv*32*32;

  int wr = wv >> 1, wc = wv & 1, lr = lane & 15, lk = lane >> 4;
  int runit = lk ^ ((lr >> 1) & 3);
  int ro = (wr*64 + lr)*32 + runit*8;
  int co = (wc*64 + lr)*32 + runit*8;
  f32x4 acc[4][4];
  #pragma unroll
  for (int i = 0; i < 4; ++i)
    #pragma unroll
    for (int j = 0; j < 4; ++j) acc[i][j] = (f32x4){0.f,0.f,0.f,0.f};

  int nst = K >> 5;                       // 12 or 48 (divisible by 3)
  #define STG(tt, b) { \
    const u16* ag_ = Ag + (size_t)(tt)*32; const u16* bg_ = Bg + (size_t)(tt)*32; \
    gload16(ag_,         &sA[b][l0]);       gload16(ag_ + rstep, &sA[b][l0 + 512]); \
    gload16(bg_,         &sB[b][l0]);       gload16(bg_ + rstep, &sB[b][l0 + 512]); }
  #define STEP(b, tt) { \
    if ((tt) + 2 < nst)      { asm volatile("s_waitcnt vmcnt(8)" ::: "memory"); } \
    else if ((tt) + 1 < nst) { asm volatile("s_waitcnt vmcnt(4)" ::: "memory"); } \
    else                     { asm volatile("s_waitcnt vmcnt(0)" ::: "memory"); } \
    __builtin_amdgcn_s_barrier(); \
    bf16x8 af[4], bfr[4]; \
    _Pragma("unroll") \
    for (int mi = 0; mi < 4; ++mi) af[mi]  = __builtin_bit_cast(bf16x8, *(const us8*)&sA[b][ro + mi*512]); \
    _Pragma("unroll") \
    for (int ni = 0; ni < 4; ++ni) bfr[ni] = __builtin_bit_cast(bf16x8, *(const us8*)&sB[b][co + ni*512]); \
    __builtin_amdgcn_s_setprio(1); \
    _Pragma("unroll") \
    for (int mi = 0; mi < 4; ++mi) \
      _Pragma("unroll") \
      for (int ni = 0; ni < 4; ++ni) \
        acc[mi][ni] = __builtin_amdgcn_mfma_f32_16x16x32_bf16(af[mi], bfr[ni], acc[mi][ni], 0, 0, 0); \
    __builtin_amdgcn_s_setprio(0); \
    asm volatile("s_waitcnt lgkmcnt(0)" ::: "memory"); \
    __builtin_amdgcn_s_barrier(); \
    if ((tt) + 3 < nst) STG((tt) + 3, b); }

  STG(0, 0); STG(1, 1); STG(2, 2);
  for (int tt = 0; tt < nst; tt += 3){
    STEP(0, tt); STEP(1, tt + 1); STEP(2, tt + 2);
  }
  #undef STEP
  #undef STG
  // last STEP's trailing barrier: all waves' ds_reads of sA/sB done.

  // ------------- vectorized epilogue via per-wave LDS transpose -------------
  float* tl = (float*)smem + wv*1088;      // [16][68] f32 per wave (private)
  float bs[4];
  #pragma unroll
  for (int ni = 0; ni < 4; ++ni) bs[ni] = bias[bn + wc*64 + ni*16 + lr];
  int rrow = lane >> 2, cb = (lane & 3) * 16;
  int colg = bn + wc*64 + cb;              // 16 consecutive cols
  #pragma unroll
  for (int mi = 0; mi < 4; ++mi){
    #pragma unroll
    for (int ni = 0; ni < 4; ++ni)
      #pragma unroll
      for (int r2 = 0; r2 < 4; ++r2)
        tl[(lk*4 + r2)*68 + ni*16 + lr] = acc[mi][ni][r2] + bs[ni];
    float vals[16];
    #pragma unroll
    for (int j = 0; j < 16; ++j) vals[j] = tl[rrow*68 + cb + j];
    int row = bm + wr*64 + mi*16 + rrow;
    if constexpr (EPI == 0){
      int which = colg / kC; int cc = colg - which*kC; int hd = cc >> 5, d0 = cc & 31;
      int win = row / kN, n = row - win*kN;
      size_t po = (size_t)(win*kHeads + hd)*2048 + n*32 + d0;
      float sc = which == 0 ? kScale : 1.f;
      bf* dst = which == 0 ? o0 : (which == 1 ? o1 : o2);
      us8 p0, p1;
      #pragma unroll
      for (int j = 0; j < 8; ++j){
        p0[j] = __builtin_bit_cast(u16, f2b(vals[j]   * sc));
        p1[j] = __builtin_bit_cast(u16, f2b(vals[j+8] * sc));
      }
      *(us8*)((u16*)dst + po)     = p0;
      *(us8*)((u16*)dst + po + 8) = p1;
    } else if constexpr (EPI == 1){
      int win = row / kN, n = row - win*kN;
      int gw = aux + win;
      int b = gw >> 6, rem = gw & 63, wh = rem >> 3, ww = rem & 7;
      int ih = n / 7, iw = n - ih*7;
      int h0 = (wh*7 + ih + 3) % 56;
      int w0 = (ww*7 + iw + 3) % 56;
      size_t base = ((size_t)b*3136 + h0*56 + w0)*kC + colg;
      const float* xr = (const float*)res;
      #pragma unroll
      for (int q4 = 0; q4 < 4; ++q4){
        f32x4 rv = *(const f32x4*)(xr + base + q4*4);
        #pragma unroll
        for (int j = 0; j < 4; ++j) vals[q4*4 + j] += rv[j];
      }
      if constexpr (ALT){
        us8 p0, p1;
        #pragma unroll
        for (int j = 0; j < 8; ++j){
          p0[j] = __builtin_bit_cast(u16, f2b(vals[j]));
          p1[j] = __builtin_bit_cast(u16, f2b(vals[j+8]));
        }
        *(us8*)((u16*)o0 + base)     = p0;
        *(us8*)((u16*)o0 + base + 8) = p1;
      } else {
        #pragma unroll
        for (int q4 = 0; q4 < 4; ++q4)
          *(f32x4*)(fo + base + q4*4) = (f32x4){vals[q4*4], vals[q4*4+1], vals[q4*4+2], vals[q4*4+3]};
      }
    } else if constexpr (EPI == 2){
      size_t base = (size_t)row*kHid + colg;
      us8 p0, p1;
      #pragma unroll
      for (int j = 0; j < 16; ++j){
        float v = gelu_f(vals[j]);
        if (j < 8) p0[j] = __builtin_bit_cast(u16, f2b(v));
        else       p1[j-8] = __builtin_bit_cast(u16, f2b(v));
      }
      *(us8*)((u16*)o0 + base)     = p0;
      *(us8*)((u16*)o0 + base + 8) = p1;
    } else {
      size_t base = (size_t)row*kC + colg;
      if constexpr (ALT){
        const u16* xb = (const u16*)res;
        us8 r0 = *(const us8*)(xb + base), r1 = *(const us8*)(xb + base + 8);
        #pragma unroll
        for (int j = 0; j < 8; ++j){
          vals[j]   += b2f(__builtin_bit_cast(bf, (u16)r0[j]));
          vals[j+8] += b2f(__builtin_bit_cast(bf, (u16)r1[j]));
        }
      } else {
        const float* xr = (const float*)res;
        #pragma unroll
        for (int q4 = 0; q4 < 4; ++q4){
          f32x4 rv = *(const f32x4*)(xr + base + q4*4);
          #pragma unroll
          for (int j = 0; j < 4; ++j) vals[q4*4 + j] += rv[j];
        }
      }
      #pragma unroll
      for (int q4 = 0; q4 < 4; ++q4)
        *(f32x4*)(fo + base + q4*4) = (f32x4){vals[q4*4], vals[q4*4+1], vals[q4*4+2], vals[q4*4+3]};
    }
  }
}

// ----------------------- MFMA window attention (v4) -----------------------
__global__ __launch_bounds__(256) void attn_k(const bf* __restrict__ qq, const bf* __restrict__ kk,
                                              const bf* __restrict__ vv, const float* __restrict__ relb,
                                              bf* __restrict__ out){
  __shared__ float rbs[169*kHeads];
  __shared__ u16 plds[4][64*64];
  int t = threadIdx.x, wv = t >> 6, l = t & 63;
  for (int i = t; i < 169*kHeads; i += 256) rbs[i] = relb[i];

  int bid = blockIdx.x*4 + wv, lw = bid / kHeads, h = bid - lw*kHeads;
  const u16* qp = (const u16*)qq + (size_t)bid*2048;
  const u16* kp = (const u16*)kk + (size_t)bid*2048;
  const u16* vp = (const u16*)vv + (size_t)bid*2048;
  int fr = l & 15, fk = l >> 4;

  bf16x8 qf[4], kf[4];
  #pragma unroll
  for (int ti = 0; ti < 4; ++ti){
    qf[ti] = __builtin_bit_cast(bf16x8, *(const us8*)(qp + (ti*16 + fr)*32 + fk*8));
    kf[ti] = __builtin_bit_cast(bf16x8, *(const us8*)(kp + (ti*16 + fr)*32 + fk*8));
  }
  f32x4 s[4][4];
  #pragma unroll
  for (int i = 0; i < 4; ++i)
    #pragma unroll
    for (int j = 0; j < 4; ++j) s[i][j] = (f32x4){0.f,0.f,0.f,0.f};
  #pragma unroll
  for (int ti = 0; ti < 4; ++ti)
    #pragma unroll
    for (int tj = 0; tj < 4; ++tj)
      s[ti][tj] = __builtin_amdgcn_mfma_f32_16x16x32_bf16(qf[ti], kf[tj], s[ti][tj], 0, 0, 0);
  __syncthreads();

  int kh[4], kw[4], cvalid[4];
  #pragma unroll
  for (int tj = 0; tj < 4; ++tj){
    int c = tj*16 + fr;
    kh[tj] = c / 7; kw[tj] = c - kh[tj]*7; cvalid[tj] = c < kN;
  }
  #pragma unroll
  for (int ti = 0; ti < 4; ++ti){
    #pragma unroll
    for (int reg = 0; reg < 4; ++reg){
      int R = ti*16 + fk*4 + reg;
      int Rc = R < kN ? R : kN-1;
      int ih = Rc / 7, iw = Rc - ih*7;
      float v[4];
      #pragma unroll
      for (int tj = 0; tj < 4; ++tj){
        float b = rbs[((ih - kh[tj] + 6)*13 + (iw - kw[tj] + 6))*kHeads + h];
        v[tj] = cvalid[tj] ? s[ti][tj][reg] + b : -1e30f;
      }
      float m = fmaxf(fmaxf(v[0], v[1]), fmaxf(v[2], v[3]));
      #pragma unroll
      for (int msk = 1; msk < 16; msk <<= 1) m = fmaxf(m, __shfl_xor(m, msk));
      float e0 = __expf(v[0]-m), e1 = __expf(v[1]-m), e2 = __expf(v[2]-m), e3 = __expf(v[3]-m);
      float sum = (e0+e1) + (e2+e3);
      #pragma unroll
      for (int msk = 1; msk < 16; msk <<= 1) sum += __shfl_xor(sum, msk);
      float inv = 1.f / sum;
      s[ti][0][reg] = e0*inv; s[ti][1][reg] = e1*inv;
      s[ti][2][reg] = e2*inv; s[ti][3][reg] = e3*inv;
    }
  }
  u16* P = plds[wv];
  #pragma unroll
  for (int ti = 0; ti < 4; ++ti)
    #pragma unroll
    for (int tj = 0; tj < 4; ++tj)
      #pragma unroll
      for (int reg = 0; reg < 4; ++reg){
        int R = ti*16 + fk*4 + reg, c = tj*16 + fr;
        P[R*64 + (((c>>3) ^ (R&7)) << 3) + (c&7)] = __builtin_bit_cast(u16, f2b(s[ti][tj][reg]));
      }
  f32x4 o[4][2];
  #pragma unroll
  for (int i = 0; i < 4; ++i){ o[i][0] = (f32x4){0.f,0.f,0.f,0.f}; o[i][1] = (f32x4){0.f,0.f,0.f,0.f}; }
  #pragma unroll
  for (int ks = 0; ks < 2; ++ks){
    bf16x8 vf[2];
    #pragma unroll
    for (int tdj = 0; tdj < 2; ++tdj){
      us8 tmp;
      #pragma unroll
      for (int j = 0; j < 8; ++j)
        tmp[j] = vp[(ks*32 + fk*8 + j)*32 + tdj*16 + fr];
      vf[tdj] = __builtin_bit_cast(bf16x8, tmp);
    }
    #pragma unroll
    for (int ti = 0; ti < 4; ++ti){
      bf16x8 af = __builtin_bit_cast(bf16x8, *(const us8*)&P[(ti*16 + fr)*64 + (((ks*4 + fk) ^ (fr&7)) << 3)]);
      #pragma unroll
      for (int tdj = 0; tdj < 2; ++tdj)
        o[ti][tdj] = __builtin_amdgcn_mfma_f32_16x16x32_bf16(af, vf[tdj], o[ti][tdj], 0, 0, 0);
    }
  }
  #pragma unroll
  for (int ti = 0; ti < 4; ++ti)
    #pragma unroll
    for (int reg = 0; reg < 4; ++reg){
      int R = ti*16 + fk*4 + reg;
      if (R < kN){
        bf* op = out + ((size_t)lw*kN + R)*kC + h*32;
        #pragma unroll
        for (int tdj = 0; tdj < 2; ++tdj)
          op[tdj*16 + fr] = f2b(o[ti][tdj][reg]);
      }
    }
}

extern "C" void kernel_launch(void* const* d_in, const int* in_sizes, int n_in,
                              void* d_out, int out_size, void* d_ws, size_t ws_size,
                              hipStream_t stream){
  (void)in_sizes; (void)n_in; (void)out_size;
  const float* x     = (const float*)d_in[0];
  const float* n1g   = (const float*)d_in[1];
  const float* n1b   = (const float*)d_in[2];
  const float* qkvw  = (const float*)d_in[3];
  const float* qkvb  = (const float*)d_in[4];
  const float* relb  = (const float*)d_in[5];
  const float* projw = (const float*)d_in[6];
  const float* projb = (const float*)d_in[7];
  const float* n2g   = (const float*)d_in[8];
  const float* n2b   = (const float*)d_in[9];
  const float* fc1w  = (const float*)d_in[10];
  const float* fc1b  = (const float*)d_in[11];
  const float* fc2w  = (const float*)d_in[12];
  const float* fc2b  = (const float*)d_in[13];
  float* out = (float*)d_out;
  char* w = (char*)d_ws;

  const size_t WINB_F = 77070336;    // 100352*384*2 (full-image bf16)
  const size_t BIGB_F = 308281344;   // 100352*1536*2 (hidden full / qkv planes)
  const size_t WTSB   = 3538944;
  const size_t planeF = (size_t)kWinsTot*kHeads*2048;   // 50,331,648 elems
  const size_t NEED_M = WINB_F + BIGB_F + WTSB + WINB_F; // 465,960,960

  if (ws_size >= NEED_M){
    // -------- merged single-pass layout --------
    bf* winbuf = (bf*)w;
    bf* big    = (bf*)(w + WINB_F);
    bf* wts    = (bf*)(w + WINB_F + BIGB_F);
    bf* x1b    = (bf*)(w + WINB_F + BIGB_F + WTSB);
    bf* qkvwt  = wts;
    bf* projwt = qkvwt + 442368;
    bf* fc1wt  = projwt + 147456;
    bf* fc2wt  = fc1wt + 589824;
    bf* qb = big; bf* kb = big + planeF; bf* vb = big + 2*planeF;

    tr_k<<<dim3((442368+255)/256), 256, 0, stream>>>(qkvw,  qkvwt, 384, 1152);
    tr_k<<<dim3((147456+255)/256), 256, 0, stream>>>(projw, projwt, 384, 384);
    tr_k<<<dim3((589824+255)/256), 256, 0, stream>>>(fc1w,  fc1wt, 384, 1536);
    tr_k<<<dim3((589824+255)/256), 256, 0, stream>>>(fc2w,  fc2wt, 1536, 384);

    ln_k<1, float><<<kRowsTot/4, 256, 0, stream>>>(x, n1g, n1b, winbuf, 0);
    gemm_k<0><<<784*9, 256, 0, stream>>>(winbuf, qkvwt, qkvb, 384, 9,
                                         qb, kb, vb, nullptr, nullptr, 0);
    attn_k<<<kWinsTot*kHeads/4, 256, 0, stream>>>(qb, kb, vb, relb, winbuf);
    gemm_k<1,1><<<784*3, 256, 0, stream>>>(winbuf, projwt, projb, 384, 3,
                                           x1b, nullptr, nullptr, nullptr, x, 0);
    ln_k<0, bf><<<kRowsTot/4, 256, 0, stream>>>(x1b, n2g, n2b, winbuf, 0);
    gemm_k<2><<<784*12, 256, 0, stream>>>(winbuf, fc1wt, fc1b, 384, 12,
                                          big, nullptr, nullptr, nullptr, nullptr, 0);
    gemm_k<3,1><<<784*3, 256, 0, stream>>>(big, fc2wt, fc2b, 1536, 3,
                                           nullptr, nullptr, nullptr, out, x1b, 0);
  } else {
    // -------- 4-chunk fallback --------
    const int cw = 512, crows = cw*kN;
    const size_t WINB = 19267584, BIGB = 77070336;
    const size_t planeC = (size_t)cw*kHeads*2048;
    bf* winbuf = (bf*)w;
    bf* big    = (bf*)(w + WINB);
    bf* wts    = (bf*)(w + WINB + BIGB);
    bf* qkvwt  = wts;
    bf* projwt = qkvwt + 442368;
    bf* fc1wt  = projwt + 147456;
    bf* fc2wt  = fc1wt + 589824;
    bf* qb = big; bf* kb = big + planeC; bf* vb = big + 2*planeC;

    tr_k<<<dim3((442368+255)/256), 256, 0, stream>>>(qkvw,  qkvwt, 384, 1152);
    tr_k<<<dim3((147456+255)/256), 256, 0, stream>>>(projw, projwt, 384, 384);
    tr_k<<<dim3((589824+255)/256), 256, 0, stream>>>(fc1w,  fc1wt, 384, 1536);
    tr_k<<<dim3((589824+255)/256), 256, 0, stream>>>(fc2w,  fc2wt, 1536, 384);

    for (int c = 0; c < 4; ++c){
      int winbase = c * cw;
      ln_k<1, float><<<crows/4, 256, 0, stream>>>(x, n1g, n1b, winbuf, winbase);
      gemm_k<0><<<196*9, 256, 0, stream>>>(winbuf, qkvwt, qkvb, 384, 9,
                                           qb, kb, vb, nullptr, nullptr, 0);
      attn_k<<<cw*kHeads/4, 256, 0, stream>>>(qb, kb, vb, relb, winbuf);
      gemm_k<1,0><<<196*3, 256, 0, stream>>>(winbuf, projwt, projb, 384, 3,
                                             nullptr, nullptr, nullptr, out, x, winbase);
    }
    for (int c = 0; c < 4; ++c){
      float* xr = out + (size_t)c * crows * kC;
      ln_k<0, float><<<crows/4, 256, 0, stream>>>(xr, n2g, n2b, winbuf, 0);
      gemm_k<2><<<196*12, 256, 0, stream>>>(winbuf, fc1wt, fc1b, 384, 12,
                                            big, nullptr, nullptr, nullptr, nullptr, 0);
      gemm_k<3,0><<<196*3, 256, 0, stream>>>(big, fc2wt, fc2b, 1536, 3,
                                             nullptr, nullptr, nullptr, xr, xr, 0);
    }
  }
}

// Round 20
// 818.370 us; speedup vs baseline: 1.0822x; 1.0246x over previous
//
#include <hip/hip_runtime.h>
#include <hip/hip_bf16.h>
#include <math.h>

using bf = __hip_bfloat16;
typedef unsigned short u16;
typedef __attribute__((ext_vector_type(8))) unsigned short us8;
typedef __attribute__((ext_vector_type(8))) __bf16 bf16x8;
typedef __attribute__((ext_vector_type(4))) float f32x4;

static constexpr int kC    = 384;
static constexpr int kHid  = 1536;
static constexpr int kHeads= 12;
static constexpr int kN    = 49;
static constexpr float kScale = 0.17677669529663687f;  // 32^-0.5

__device__ __forceinline__ float b2f(bf v){ return __bfloat162float(v); }
__device__ __forceinline__ bf    f2b(float v){ return __float2bfloat16(v); }
__device__ __forceinline__ float ldf(const float* p){ return *p; }
__device__ __forceinline__ float ldf(const bf* p){ return b2f(*p); }

// gelu tanh-approx with raw HW ops: v_exp_f32 + v_rcp_f32
__device__ __forceinline__ float gelu_f(float v){
  float v2 = v*v;
  float y  = v * (0.7978845608f + 0.0356774081f*v2);
  float e  = __builtin_amdgcn_exp2f(y * 2.885390082f);
  float r  = __builtin_amdgcn_rcpf(1.f + e);
  return v - v*r;
}

__device__ __forceinline__ void gload16(const void* g, void* l){
  __builtin_amdgcn_global_load_lds(
      (const __attribute__((address_space(1))) void*)g,
      (__attribute__((address_space(3))) void*)l, 16, 0, 0);
}

// ---------------- weight transpose: out[n*K+k] = bf16(in[k*N+n]) ----------
__global__ void tr_k(const float* __restrict__ in, bf* __restrict__ out, int K, int N){
  int i = blockIdx.x*256 + threadIdx.x;
  if (i < K*N){ int k = i / N, n = i - k*N; out[(size_t)n*K + k] = f2b(in[i]); }
}

// ---- LayerNorm. GATHER=1: fused shift + window partition ----
template<int GATHER, typename TIN>
__global__ __launch_bounds__(256) void ln_k(const TIN* __restrict__ x, const float* __restrict__ g,
                                            const float* __restrict__ be, bf* __restrict__ out,
                                            int winbase){
  int wv = threadIdx.x >> 6, lane = threadIdx.x & 63;
  int lr = blockIdx.x*4 + wv;
  const TIN* src;
  if constexpr (GATHER){
    int win = lr / kN, n = lr - win*kN;
    int gw = winbase + win;
    int b = gw >> 6, rem = gw & 63, wh = rem >> 3, ww = rem & 7;
    int ih = n / 7, iw = n - ih*7;
    int h0 = (wh*7 + ih + 3) % 56;
    int w0 = (ww*7 + iw + 3) % 56;
    src = x + ((size_t)b*3136 + h0*56 + w0) * kC;
  } else {
    src = x + (size_t)lr * kC;
  }
  float vals[6]; float s = 0.f, sq = 0.f;
  #pragma unroll
  for (int j = 0; j < 6; ++j){ float f = ldf(src + j*64 + lane); vals[j] = f; s += f; sq += f*f; }
  #pragma unroll
  for (int o = 32; o > 0; o >>= 1){ s += __shfl_down(s, o); sq += __shfl_down(sq, o); }
  s = __shfl(s, 0); sq = __shfl(sq, 0);
  float mean = s * (1.f/384.f);
  float var  = sq * (1.f/384.f) - mean*mean;
  float rstd = rsqrtf(var + 1e-5f);
  bf* dst = out + (size_t)lr * kC;
  #pragma unroll
  for (int j = 0; j < 6; ++j){
    int c = j*64 + lane;
    dst[c] = f2b((vals[j]-mean)*rstd*g[c] + be[c]);
  }
}

// ---- 3-buffer pipelined 128x128 bf16 MFMA GEMM, BK=32, counted vmcnt ----
template<int EPI, int ALT = 0>
__global__ __launch_bounds__(256, 3) void gemm_k(const bf* __restrict__ A, const bf* __restrict__ Wt,
                                                 const float* __restrict__ bias, int K, int nbn,
                                                 bf* o0, bf* o1, bf* o2,
                                                 float* fo, const void* res, int aux){
  __shared__ char smem[49152];
  u16 (*sA)[4096] = (u16(*)[4096])smem;            // 3 x 8 KB
  u16 (*sB)[4096] = (u16(*)[4096])(smem + 24576);  // 3 x 8 KB
  int nwg = gridDim.x, id = blockIdx.x;
  int q = nwg >> 3, r = nwg & 7, xcd = id & 7, off = id >> 3;
  int swz = (xcd < r ? xcd*(q+1) : r*(q+1) + (xcd-r)*q) + off;
  int bm = (swz / nbn) << 7, bn = (swz % nbn) << 7;

  int t = threadIdx.x, lane = t & 63, wv = t >> 6;
  int scol = ((lane & 3) ^ ((lane >> 3) & 3)) * 8;
  const u16* Ag = (const u16*)A  + (size_t)(bm + wv*32 + (lane >> 2))*K + scol;
  const u16* Bg = (const u16*)Wt + (size_t)(bn + wv*32 + (lane >> 2))*K + scol;
  size_t rstep = (size_t)16 * K;
  int l0 = wv*32*32;

  int wr = wv >> 1, wc = wv & 1, lr = lane & 15, lk = lane >> 4;
  int runit = lk ^ ((lr >> 1) & 3);
  int ro = (wr*64 + lr)*32 + runit*8;
  int co = (wc*64 + lr)*32 + runit*8;
  f32x4 acc[4][4];
  #pragma unroll
  for (int i = 0; i < 4; ++i)
    #pragma unroll
    for (int j = 0; j < 4; ++j) acc[i][j] = (f32x4){0.f,0.f,0.f,0.f};

  int nst = K >> 5;                       // 12 or 48 (divisible by 3)
  #define STG(tt, b) { \
    const u16* ag_ = Ag + (size_t)(tt)*32; const u16* bg_ = Bg + (size_t)(tt)*32; \
    gload16(ag_,         &sA[b][l0]);       gload16(ag_ + rstep, &sA[b][l0 + 512]); \
    gload16(bg_,         &sB[b][l0]);       gload16(bg_ + rstep, &sB[b][l0 + 512]); }
  #define STEP(b, tt) { \
    if ((tt) + 2 < nst)      { asm volatile("s_waitcnt vmcnt(8)" ::: "memory"); } \
    else if ((tt) + 1 < nst) { asm volatile("s_waitcnt vmcnt(4)" ::: "memory"); } \
    else                     { asm volatile("s_waitcnt vmcnt(0)" ::: "memory"); } \
    __builtin_amdgcn_s_barrier(); \
    bf16x8 af[4], bfr[4]; \
    _Pragma("unroll") \
    for (int mi = 0; mi < 4; ++mi) af[mi]  = __builtin_bit_cast(bf16x8, *(const us8*)&sA[b][ro + mi*512]); \
    _Pragma("unroll") \
    for (int ni = 0; ni < 4; ++ni) bfr[ni] = __builtin_bit_cast(bf16x8, *(const us8*)&sB[b][co + ni*512]); \
    __builtin_amdgcn_s_setprio(1); \
    _Pragma("unroll") \
    for (int mi = 0; mi < 4; ++mi) \
      _Pragma("unroll") \
      for (int ni = 0; ni < 4; ++ni) \
        acc[mi][ni] = __builtin_amdgcn_mfma_f32_16x16x32_bf16(af[mi], bfr[ni], acc[mi][ni], 0, 0, 0); \
    __builtin_amdgcn_s_setprio(0); \
    asm volatile("s_waitcnt lgkmcnt(0)" ::: "memory"); \
    __builtin_amdgcn_s_barrier(); \
    if ((tt) + 3 < nst) STG((tt) + 3, b); }

  STG(0, 0); STG(1, 1); STG(2, 2);
  for (int tt = 0; tt < nst; tt += 3){
    STEP(0, tt); STEP(1, tt + 1); STEP(2, tt + 2);
  }
  #undef STEP
  #undef STG

  // ------------- vectorized epilogue via per-wave LDS transpose -------------
  float* tl = (float*)smem + wv*1088;      // [16][68] f32 per wave (private)
  float bs[4];
  #pragma unroll
  for (int ni = 0; ni < 4; ++ni) bs[ni] = bias[bn + wc*64 + ni*16 + lr];
  int rrow = lane >> 2, cb = (lane & 3) * 16;
  int colg = bn + wc*64 + cb;
  #pragma unroll
  for (int mi = 0; mi < 4; ++mi){
    #pragma unroll
    for (int ni = 0; ni < 4; ++ni)
      #pragma unroll
      for (int r2 = 0; r2 < 4; ++r2)
        tl[(lk*4 + r2)*68 + ni*16 + lr] = acc[mi][ni][r2] + bs[ni];
    float vals[16];
    #pragma unroll
    for (int j = 0; j < 16; ++j) vals[j] = tl[rrow*68 + cb + j];
    int row = bm + wr*64 + mi*16 + rrow;
    if constexpr (EPI == 0){
      int which = colg / kC; int cc = colg - which*kC; int hd = cc >> 5, d0 = cc & 31;
      int win = row / kN, n = row - win*kN;
      size_t po = (size_t)(win*kHeads + hd)*2048 + n*32 + d0;
      float sc = which == 0 ? kScale : 1.f;
      bf* dst = which == 0 ? o0 : (which == 1 ? o1 : o2);
      us8 p0, p1;
      #pragma unroll
      for (int j = 0; j < 8; ++j){
        p0[j] = __builtin_bit_cast(u16, f2b(vals[j]   * sc));
        p1[j] = __builtin_bit_cast(u16, f2b(vals[j+8] * sc));
      }
      *(us8*)((u16*)dst + po)     = p0;
      *(us8*)((u16*)dst + po + 8) = p1;
    } else if constexpr (EPI == 1){
      int win = row / kN, n = row - win*kN;
      int gw = aux + win;
      int b = gw >> 6, rem = gw & 63, wh = rem >> 3, ww = rem & 7;
      int ih = n / 7, iw = n - ih*7;
      int h0 = (wh*7 + ih + 3) % 56;
      int w0 = (ww*7 + iw + 3) % 56;
      size_t base = ((size_t)b*3136 + h0*56 + w0)*kC + colg;
      const float* xr = (const float*)res;
      #pragma unroll
      for (int q4 = 0; q4 < 4; ++q4){
        f32x4 rv = *(const f32x4*)(xr + base + q4*4);
        #pragma unroll
        for (int j = 0; j < 4; ++j) vals[q4*4 + j] += rv[j];
      }
      if constexpr (ALT){
        us8 p0, p1;
        #pragma unroll
        for (int j = 0; j < 8; ++j){
          p0[j] = __builtin_bit_cast(u16, f2b(vals[j]));
          p1[j] = __builtin_bit_cast(u16, f2b(vals[j+8]));
        }
        *(us8*)((u16*)o0 + base)     = p0;
        *(us8*)((u16*)o0 + base + 8) = p1;
      } else {
        #pragma unroll
        for (int q4 = 0; q4 < 4; ++q4)
          *(f32x4*)(fo + base + q4*4) = (f32x4){vals[q4*4], vals[q4*4+1], vals[q4*4+2], vals[q4*4+3]};
      }
    } else if constexpr (EPI == 2){
      size_t base = (size_t)row*kHid + colg;
      us8 p0, p1;
      #pragma unroll
      for (int j = 0; j < 16; ++j){
        float v = gelu_f(vals[j]);
        if (j < 8) p0[j] = __builtin_bit_cast(u16, f2b(v));
        else       p1[j-8] = __builtin_bit_cast(u16, f2b(v));
      }
      *(us8*)((u16*)o0 + base)     = p0;
      *(us8*)((u16*)o0 + base + 8) = p1;
    } else {
      size_t base = (size_t)row*kC + colg;
      if constexpr (ALT){
        const u16* xb = (const u16*)res;
        us8 r0 = *(const us8*)(xb + base), r1 = *(const us8*)(xb + base + 8);
        #pragma unroll
        for (int j = 0; j < 8; ++j){
          vals[j]   += b2f(__builtin_bit_cast(bf, (u16)r0[j]));
          vals[j+8] += b2f(__builtin_bit_cast(bf, (u16)r1[j]));
        }
      } else {
        const float* xr = (const float*)res;
        #pragma unroll
        for (int q4 = 0; q4 < 4; ++q4){
          f32x4 rv = *(const f32x4*)(xr + base + q4*4);
          #pragma unroll
          for (int j = 0; j < 4; ++j) vals[q4*4 + j] += rv[j];
        }
      }
      #pragma unroll
      for (int q4 = 0; q4 < 4; ++q4)
        *(f32x4*)(fo + base + q4*4) = (f32x4){vals[q4*4], vals[q4*4+1], vals[q4*4+2], vals[q4*4+3]};
    }
  }
}

// ----------------------- MFMA window attention (v4) -----------------------
__global__ __launch_bounds__(256) void attn_k(const bf* __restrict__ qq, const bf* __restrict__ kk,
                                              const bf* __restrict__ vv, const float* __restrict__ relb,
                                              bf* __restrict__ out){
  __shared__ float rbs[169*kHeads];
  __shared__ u16 plds[4][64*64];
  int t = threadIdx.x, wv = t >> 6, l = t & 63;
  for (int i = t; i < 169*kHeads; i += 256) rbs[i] = relb[i];

  int bid = blockIdx.x*4 + wv, lw = bid / kHeads, h = bid - lw*kHeads;
  const u16* qp = (const u16*)qq + (size_t)bid*2048;
  const u16* kp = (const u16*)kk + (size_t)bid*2048;
  const u16* vp = (const u16*)vv + (size_t)bid*2048;
  int fr = l & 15, fk = l >> 4;

  bf16x8 qf[4], kf[4];
  #pragma unroll
  for (int ti = 0; ti < 4; ++ti){
    qf[ti] = __builtin_bit_cast(bf16x8, *(const us8*)(qp + (ti*16 + fr)*32 + fk*8));
    kf[ti] = __builtin_bit_cast(bf16x8, *(const us8*)(kp + (ti*16 + fr)*32 + fk*8));
  }
  f32x4 s[4][4];
  #pragma unroll
  for (int i = 0; i < 4; ++i)
    #pragma unroll
    for (int j = 0; j < 4; ++j) s[i][j] = (f32x4){0.f,0.f,0.f,0.f};
  #pragma unroll
  for (int ti = 0; ti < 4; ++ti)
    #pragma unroll
    for (int tj = 0; tj < 4; ++tj)
      s[ti][tj] = __builtin_amdgcn_mfma_f32_16x16x32_bf16(qf[ti], kf[tj], s[ti][tj], 0, 0, 0);
  __syncthreads();

  int kh[4], kw[4], cvalid[4];
  #pragma unroll
  for (int tj = 0; tj < 4; ++tj){
    int c = tj*16 + fr;
    kh[tj] = c / 7; kw[tj] = c - kh[tj]*7; cvalid[tj] = c < kN;
  }
  #pragma unroll
  for (int ti = 0; ti < 4; ++ti){
    #pragma unroll
    for (int reg = 0; reg < 4; ++reg){
      int R = ti*16 + fk*4 + reg;
      int Rc = R < kN ? R : kN-1;
      int ih = Rc / 7, iw = Rc - ih*7;
      float v[4];
      #pragma unroll
      for (int tj = 0; tj < 4; ++tj){
        float b = rbs[((ih - kh[tj] + 6)*13 + (iw - kw[tj] + 6))*kHeads + h];
        v[tj] = cvalid[tj] ? s[ti][tj][reg] + b : -1e30f;
      }
      float m = fmaxf(fmaxf(v[0], v[1]), fmaxf(v[2], v[3]));
      #pragma unroll
      for (int msk = 1; msk < 16; msk <<= 1) m = fmaxf(m, __shfl_xor(m, msk));
      float e0 = __expf(v[0]-m), e1 = __expf(v[1]-m), e2 = __expf(v[2]-m), e3 = __expf(v[3]-m);
      float sum = (e0+e1) + (e2+e3);
      #pragma unroll
      for (int msk = 1; msk < 16; msk <<= 1) sum += __shfl_xor(sum, msk);
      float inv = 1.f / sum;
      s[ti][0][reg] = e0*inv; s[ti][1][reg] = e1*inv;
      s[ti][2][reg] = e2*inv; s[ti][3][reg] = e3*inv;
    }
  }
  u16* P = plds[wv];
  #pragma unroll
  for (int ti = 0; ti < 4; ++ti)
    #pragma unroll
    for (int tj = 0; tj < 4; ++tj)
      #pragma unroll
      for (int reg = 0; reg < 4; ++reg){
        int R = ti*16 + fk*4 + reg, c = tj*16 + fr;
        P[R*64 + (((c>>3) ^ (R&7)) << 3) + (c&7)] = __builtin_bit_cast(u16, f2b(s[ti][tj][reg]));
      }
  f32x4 o[4][2];
  #pragma unroll
  for (int i = 0; i < 4; ++i){ o[i][0] = (f32x4){0.f,0.f,0.f,0.f}; o[i][1] = (f32x4){0.f,0.f,0.f,0.f}; }
  #pragma unroll
  for (int ks = 0; ks < 2; ++ks){
    bf16x8 vf[2];
    #pragma unroll
    for (int tdj = 0; tdj < 2; ++tdj){
      us8 tmp;
      #pragma unroll
      for (int j = 0; j < 8; ++j)
        tmp[j] = vp[(ks*32 + fk*8 + j)*32 + tdj*16 + fr];
      vf[tdj] = __builtin_bit_cast(bf16x8, tmp);
    }
    #pragma unroll
    for (int ti = 0; ti < 4; ++ti){
      bf16x8 af = __builtin_bit_cast(bf16x8, *(const us8*)&P[(ti*16 + fr)*64 + (((ks*4 + fk) ^ (fr&7)) << 3)]);
      #pragma unroll
      for (int tdj = 0; tdj < 2; ++tdj)
        o[ti][tdj] = __builtin_amdgcn_mfma_f32_16x16x32_bf16(af, vf[tdj], o[ti][tdj], 0, 0, 0);
    }
  }
  #pragma unroll
  for (int ti = 0; ti < 4; ++ti)
    #pragma unroll
    for (int reg = 0; reg < 4; ++reg){
      int R = ti*16 + fk*4 + reg;
      if (R < kN){
        bf* op = out + ((size_t)lw*kN + R)*kC + h*32;
        #pragma unroll
        for (int tdj = 0; tdj < 2; ++tdj)
          op[tdj*16 + fr] = f2b(o[ti][tdj][reg]);
      }
    }
}

extern "C" void kernel_launch(void* const* d_in, const int* in_sizes, int n_in,
                              void* d_out, int out_size, void* d_ws, size_t ws_size,
                              hipStream_t stream){
  (void)in_sizes; (void)n_in; (void)out_size;
  const float* x     = (const float*)d_in[0];
  const float* n1g   = (const float*)d_in[1];
  const float* n1b   = (const float*)d_in[2];
  const float* qkvw  = (const float*)d_in[3];
  const float* qkvb  = (const float*)d_in[4];
  const float* relb  = (const float*)d_in[5];
  const float* projw = (const float*)d_in[6];
  const float* projb = (const float*)d_in[7];
  const float* n2g   = (const float*)d_in[8];
  const float* n2b   = (const float*)d_in[9];
  const float* fc1w  = (const float*)d_in[10];
  const float* fc1b  = (const float*)d_in[11];
  const float* fc2w  = (const float*)d_in[12];
  const float* fc2b  = (const float*)d_in[13];
  float* out = (float*)d_out;
  char* w = (char*)d_ws;

  const size_t WTSB = 3538944;

  // -------- 2-chunk L3-blocked layout (chunk intermediates fit 256MB L3) ----
  const int cw = 1024, crows = cw*kN;                 // 50176 rows/chunk
  const size_t planeC = (size_t)cw*kHeads*2048;       // 25,165,824 elems
  const size_t WINB_C = (size_t)crows*kC*2;           // 38,535,168
  const size_t BIGB_C = (size_t)crows*kHid*2;         // 154,140,672 (>= 3*planeC*2)
  const size_t X1B    = (size_t)2*crows*kC*2;         // 77,070,336 (full image)
  const size_t NEED   = WINB_C + BIGB_C + WTSB + X1B; // ~273 MB

  if (ws_size >= NEED){
    bf* winbuf = (bf*)w;
    bf* big    = (bf*)(w + WINB_C);
    bf* wts    = (bf*)(w + WINB_C + BIGB_C);
    bf* x1b    = (bf*)(w + WINB_C + BIGB_C + WTSB);
    bf* qkvwt  = wts;
    bf* projwt = qkvwt + 442368;
    bf* fc1wt  = projwt + 147456;
    bf* fc2wt  = fc1wt + 589824;
    bf* qb = big; bf* kb = big + planeC; bf* vb = big + 2*planeC;

    tr_k<<<dim3((442368+255)/256), 256, 0, stream>>>(qkvw,  qkvwt, 384, 1152);
    tr_k<<<dim3((147456+255)/256), 256, 0, stream>>>(projw, projwt, 384, 384);
    tr_k<<<dim3((589824+255)/256), 256, 0, stream>>>(fc1w,  fc1wt, 384, 1536);
    tr_k<<<dim3((589824+255)/256), 256, 0, stream>>>(fc2w,  fc2wt, 1536, 384);

    for (int c = 0; c < 2; ++c){
      int winbase = c * cw;
      size_t roff = (size_t)c * crows;
      // attention path (chunk intermediates L3-resident)
      ln_k<1, float><<<crows/4, 256, 0, stream>>>(x, n1g, n1b, winbuf, winbase);
      gemm_k<0><<<392*9, 256, 0, stream>>>(winbuf, qkvwt, qkvb, 384, 9,
                                           qb, kb, vb, nullptr, nullptr, 0);
      attn_k<<<cw*kHeads/4, 256, 0, stream>>>(qb, kb, vb, relb, winbuf);
      gemm_k<1,1><<<392*3, 256, 0, stream>>>(winbuf, projwt, projb, 384, 3,
                                             x1b, nullptr, nullptr, nullptr, x, winbase);
      // MLP path on this chunk while x1b/hidden are L3-hot
      ln_k<0, bf><<<crows/4, 256, 0, stream>>>(x1b + roff*kC, n2g, n2b, winbuf, 0);
      gemm_k<2><<<392*12, 256, 0, stream>>>(winbuf, fc1wt, fc1b, 384, 12,
                                            big, nullptr, nullptr, nullptr, nullptr, 0);
      gemm_k<3,1><<<392*3, 256, 0, stream>>>(big, fc2wt, fc2b, 1536, 3,
                                             nullptr, nullptr, nullptr,
                                             out + roff*kC, x1b + roff*kC, 0);
    }
  } else {
    // -------- 4-chunk fallback (f32 x1 path, smaller ws) --------
    const int cw4 = 512, crows4 = cw4*kN;
    const size_t WINB = 19267584, BIGB = 77070336;
    const size_t planeC4 = (size_t)cw4*kHeads*2048;
    bf* winbuf = (bf*)w;
    bf* big    = (bf*)(w + WINB);
    bf* wts    = (bf*)(w + WINB + BIGB);
    bf* qkvwt  = wts;
    bf* projwt = qkvwt + 442368;
    bf* fc1wt  = projwt + 147456;
    bf* fc2wt  = fc1wt + 589824;
    bf* qb = big; bf* kb = big + planeC4; bf* vb = big + 2*planeC4;

    tr_k<<<dim3((442368+255)/256), 256, 0, stream>>>(qkvw,  qkvwt, 384, 1152);
    tr_k<<<dim3((147456+255)/256), 256, 0, stream>>>(projw, projwt, 384, 384);
    tr_k<<<dim3((589824+255)/256), 256, 0, stream>>>(fc1w,  fc1wt, 384, 1536);
    tr_k<<<dim3((589824+255)/256), 256, 0, stream>>>(fc2w,  fc2wt, 1536, 384);

    for (int c = 0; c < 4; ++c){
      int winbase = c * cw4;
      ln_k<1, float><<<crows4/4, 256, 0, stream>>>(x, n1g, n1b, winbuf, winbase);
      gemm_k<0><<<196*9, 256, 0, stream>>>(winbuf, qkvwt, qkvb, 384, 9,
                                           qb, kb, vb, nullptr, nullptr, 0);
      attn_k<<<cw4*kHeads/4, 256, 0, stream>>>(qb, kb, vb, relb, winbuf);
      gemm_k<1,0><<<196*3, 256, 0, stream>>>(winbuf, projwt, projb, 384, 3,
                                             nullptr, nullptr, nullptr, out, x, winbase);
    }
    for (int c = 0; c < 4; ++c){
      float* xr = out + (size_t)c * crows4 * kC;
      ln_k<0, float><<<crows4/4, 256, 0, stream>>>(xr, n2g, n2b, winbuf, 0);
      gemm_k<2><<<196*12, 256, 0, stream>>>(winbuf, fc1wt, fc1b, 384, 12,
                                            big, nullptr, nullptr, nullptr, nullptr, 0);
      gemm_k<3,0><<<196*3, 256, 0, stream>>>(big, fc2wt, fc2b, 1536, 3,
                                             nullptr, nullptr, nullptr, xr, xr, 0);
    }
  }
}